// Round 1
// baseline (253.907 us; speedup 1.0000x reference)
//
#include <hip/hip_runtime.h>
#include <math.h>

// Problem constants
#define NB 128     // batch
#define NC 128     // channels
#define NN 170     // nodes
#define NT 12      // length
#define MP 176     // padded row stride for Ed/P (halfs); 176*2B = 352B, 16B-aligned rows
#define BSROW 196  // LDS row stride for K2 staged Es tiles (f32)

// Workspace regions (halfs)
#define ED_SZ ((size_t)NB * NN * MP)   // 3,829,760 halfs = 7.3 MB
#define P_SZ  ((size_t)NB * NN * MP)   // 3,829,760 halfs = 7.3 MB

// MFMA fragment / accumulator types (16x16x32 f16: 8 halfs per operand lane)
typedef _Float16 h8 __attribute__((ext_vector_type(8)));
typedef _Float16 h4 __attribute__((ext_vector_type(4)));
typedef __fp16   g2 __attribute__((ext_vector_type(2)));  // cvt_pkrtz return type
typedef float    f4 __attribute__((ext_vector_type(4)));

// tanh via hw exp+rcp: ~6 VALU ops vs ~30+ for libm tanhf. rel err ~1e-6.
__device__ __forceinline__ float fast_tanh(float x) {
    float cx = fminf(fmaxf(x, -15.f), 15.f);        // avoid inf/inf
    float e  = __expf(2.f * cx);                    // v_exp_f32
    return (e - 1.f) * __builtin_amdgcn_rcpf(e + 1.f);
}

// ---------------------------------------------------------------------------
// K2 (fused K0+K1+K2): Ed[b][n][m] = tanh( sum_c (sum_t x[b][c][n][t]) * Es[c][m] )
// HBM-bound at the 133 MB x-read floor (~22us). Es is loaded directly (87 KB,
// L2-resident after first block) with the m>=170 pad zeroed in the stage —
// the former k0 pad kernel is gone. Ed is written as f16 (cvt_pkrtz after
// tanh — bit-identical to the old f32-store + k3-side cvt_pkrtz, since the
// same op just moved here), halving Ed traffic and k3's staging work.
// ---------------------------------------------------------------------------
__global__ __launch_bounds__(256) void k2_fused(const float* __restrict__ x,
                                                const float* __restrict__ Es,
                                                _Float16* __restrict__ Ed) {
    const int b = blockIdx.y, n0 = blockIdx.x * 32;
    const int t = threadIdx.x, tx = t & 15, ty = t >> 4;
    __shared__ __align__(16) float As[16][36];      // [c][n], 2.3 KB
    __shared__ __align__(16) float Bs[16][BSROW];   // [c][m], 12.5 KB

    float acc[2][12] = {};
    for (int c0 = 0; c0 < NC; c0 += 16) {
        __syncthreads();
        {   // A-stage: 512 (c,n) groups; thread handles groups 2t, 2t+1.
            int c  = t >> 4;
            int nn = (t & 15) * 2;
            #pragma unroll
            for (int u = 0; u < 2; ++u) {
                int n = n0 + nn + u;
                float s = 0.f;
                if (n < NN) {
                    const float4* p = reinterpret_cast<const float4*>(
                        x + ((size_t)((b * NC + c0 + c) * NN) + n) * NT);
                    float4 f0 = p[0], f1 = p[1], f2 = p[2];
                    s = ((f0.x + f0.y) + (f0.z + f0.w))
                      + ((f1.x + f1.y) + (f1.z + f1.w))
                      + ((f2.x + f2.y) + (f2.z + f2.w));
                }
                As[c][nn + u] = s;
            }
        }
        // B-stage: 16c x 176m scalars direct from Es (L2-hot), pad cols zeroed.
        #pragma unroll
        for (int it = 0; it < 11; ++it) {
            int idx = t + it * 256;                  // [0, 2816) = 16*176
            int c = idx / 176, m = idx - c * 176;
            Bs[c][m] = (m < NN) ? Es[(c0 + c) * NN + m] : 0.f;
        }
        __syncthreads();
        #pragma unroll
        for (int cc = 0; cc < 16; ++cc) {
            float2 av = *reinterpret_cast<const float2*>(&As[cc][ty * 2]);
            float a[2] = {av.x, av.y};
            float bb[12];
            #pragma unroll
            for (int off = 0; off < 3; ++off) {
                float4 bv = *reinterpret_cast<const float4*>(&Bs[cc][tx * 4 + off * 64]);
                bb[off * 4 + 0] = bv.x; bb[off * 4 + 1] = bv.y;
                bb[off * 4 + 2] = bv.z; bb[off * 4 + 3] = bv.w;
            }
            #pragma unroll
            for (int ii = 0; ii < 2; ++ii)
                #pragma unroll
                for (int jj = 0; jj < 12; ++jj)
                    acc[ii][jj] = fmaf(a[ii], bb[jj], acc[ii][jj]);
        }
    }
    #pragma unroll
    for (int ii = 0; ii < 2; ++ii) {
        int n = n0 + ty * 2 + ii;
        if (n >= NN) continue;
        _Float16* Erow = Ed + ((size_t)(b * NN + n)) * MP;
        #pragma unroll
        for (int off = 0; off < 3; ++off) {
            int m = tx * 4 + off * 64;
            if (m >= MP) continue;
            g2 lo = __builtin_amdgcn_cvt_pkrtz(fast_tanh(acc[ii][off * 4 + 0]),
                                               fast_tanh(acc[ii][off * 4 + 1]));
            g2 hi = __builtin_amdgcn_cvt_pkrtz(fast_tanh(acc[ii][off * 4 + 2]),
                                               fast_tanh(acc[ii][off * 4 + 3]));
            h4 hv;
            hv[0] = (_Float16)lo[0]; hv[1] = (_Float16)lo[1];
            hv[2] = (_Float16)hi[0]; hv[3] = (_Float16)hi[1];
            *reinterpret_cast<h4*>(Erow + m) = hv;   // 8B store
        }
    }
}

// ---------------------------------------------------------------------------
// K3 (MFMA): scores = relu(Ed[b]·Ed[b]^T / sqrt(C)), row softmax, write P (f16).
// Ed now arrives as f16, so each 32-col chunk stages as 768 16B copies
// (3 iters/thread, no cvt) instead of 1536 float4+cvt slots (6 iters).
//  - C = A*B^T pattern (m97-family, HW-verified): A-frag = rows r0+rt*16+l15,
//    B-frag = rows ct*16+l15, same per-lane layout (8 contiguous k at quad*8).
//    4 waves x (2 row-tiles x 3 col-tiles), 6 mfma_f32_16x16x32_f16 / wave / chunk.
//  - D layout (m89-verified): col=lane&15, row=quad*4+reg.
//  - Softmax: wave w owns rows w*8..w*8+7; lane covers k=lane,+64,+128 (masked
//    at 170). P stored f16: adds <=2^-12 abs err to the later mean — far under
//    the ~1% f16-score perturbation already proven benign (absmax 0.0).
// ---------------------------------------------------------------------------
__global__ __launch_bounds__(256) void k3_scores_mfma(const _Float16* __restrict__ Ed,
                                                      _Float16* __restrict__ P) {
    const int b = blockIdx.y, r0 = blockIdx.x * 32;
    const int t = threadIdx.x;
    const int lane = t & 63, wave = t >> 6;
    const int l15 = lane & 15, quad = lane >> 4;

    __shared__ __align__(16) _Float16 Eh[192 * 40];  // [k-row][chunk k], stride 40 halfs (80B)
    __shared__ __align__(16) float    Sc[32 * 204];  // [n_local][k], stride 204

    const _Float16* __restrict__ Edb = Ed + (size_t)b * NN * MP;

    f4 acc[2][3] = {};                               // 2 row-tiles x 3 col-tiles
    for (int mc = 0; mc < 192; mc += 32) {
        __syncthreads();
        // Stage: 192 rows x 4 h8-slots = 768 16B copies -> 3 iters/thread.
        #pragma unroll
        for (int it = 0; it < 3; ++it) {
            int idx = t + it * 256;                  // [0,768)
            int row = idx >> 2, q = idx & 3;
            int col = mc + q * 8;
            h8 v = {};
            if (row < NN && col < MP)                // col mult of 8; col<176 => +7 in-bounds
                v = *reinterpret_cast<const h8*>(Edb + (size_t)row * MP + col);
            *reinterpret_cast<h8*>(&Eh[row * 40 + q * 8]) = v;   // 16B ds_write
        }
        __syncthreads();
        const int ko = quad * 8;                     // k-offset within chunk
        h8 a0 = *reinterpret_cast<const h8*>(&Eh[(r0 + l15) * 40 + ko]);
        h8 a1 = *reinterpret_cast<const h8*>(&Eh[(r0 + 16 + l15) * 40 + ko]);
        #pragma unroll
        for (int ci = 0; ci < 3; ++ci) {
            int kc = (wave * 3 + ci) * 16 + l15;     // B base row (= score col)
            h8 bf = *reinterpret_cast<const h8*>(&Eh[kc * 40 + ko]);
            acc[0][ci] = __builtin_amdgcn_mfma_f32_16x16x32_f16(a0, bf, acc[0][ci], 0, 0, 0);
            acc[1][ci] = __builtin_amdgcn_mfma_f32_16x16x32_f16(a1, bf, acc[1][ci], 0, 0, 0);
        }
    }

    // Scatter scaled+relu scores to Sc.
    const float scale = 0.08838834764831845f;        // 1/sqrt(128)
    #pragma unroll
    for (int rt = 0; rt < 2; ++rt)
        #pragma unroll
        for (int ci = 0; ci < 3; ++ci) {
            int col = (wave * 3 + ci) * 16 + l15;
            #pragma unroll
            for (int reg = 0; reg < 4; ++reg) {
                int rloc = rt * 16 + quad * 4 + reg;
                Sc[rloc * 204 + col] = fmaxf(acc[rt][ci][reg] * scale, 0.f);
            }
        }
    __syncthreads();

    // Softmax: wave w owns rows w*8 .. w*8+7. relu => valid values >= 0.
    for (int rr = 0; rr < 8; ++rr) {
        int r = wave * 8 + rr;
        int n = r0 + r;
        if (n >= NN) continue;                       // uniform per iteration
        float v0 = Sc[r * 204 + lane];
        float v1 = Sc[r * 204 + lane + 64];
        int  k2i = lane + 128;
        bool has2 = (k2i < NN);
        float v2 = has2 ? Sc[r * 204 + k2i] : -1.f;
        float m = fmaxf(fmaxf(v0, v1), v2);
        #pragma unroll
        for (int off = 32; off; off >>= 1) m = fmaxf(m, __shfl_xor(m, off, 64));
        float e0 = __expf(v0 - m);
        float e1 = __expf(v1 - m);
        float e2 = has2 ? __expf(v2 - m) : 0.f;
        float s = e0 + e1 + e2;
        #pragma unroll
        for (int off = 32; off; off >>= 1) s += __shfl_xor(s, off, 64);
        float inv = 1.f / s;
        _Float16* Pr = P + ((size_t)(b * NN + n)) * MP;
        Pr[lane]      = (_Float16)(e0 * inv);
        Pr[lane + 64] = (_Float16)(e1 * inv);
        if (has2) Pr[k2i] = (_Float16)(e2 * inv);
    }
}

// ---------------------------------------------------------------------------
// K4 (merged K4a+K4b): mean over batch + threshold in one pass. P is f16 and
// L2/L3-resident (7.3 MB); each thread owns one (n,k), 128 independent
// strided loads (4-way partial sums for ILP), then thresholds. Reads only
// k<170 per row, so P's pad cols may stay unwritten.
// ---------------------------------------------------------------------------
__global__ __launch_bounds__(256) void k4_mean_thresh(const _Float16* __restrict__ P,
                                                      float* __restrict__ out) {
    int p = blockIdx.x * 256 + threadIdx.x;
    if (p >= NN * NN) return;
    int n = p / NN, k = p - n * NN;
    const _Float16* base = P + (size_t)n * MP + k;
    float s0 = 0.f, s1 = 0.f, s2 = 0.f, s3 = 0.f;
    #pragma unroll
    for (int b = 0; b < NB; b += 4) {
        s0 += (float)base[(size_t)(b + 0) * NN * MP];
        s1 += (float)base[(size_t)(b + 1) * NN * MP];
        s2 += (float)base[(size_t)(b + 2) * NN * MP];
        s3 += (float)base[(size_t)(b + 3) * NN * MP];
    }
    float s = (s0 + s1) + (s2 + s3);
    out[p] = (s * (1.f / 128.f) > 0.5f) ? 1.f : 0.f;
}

// ---------------------------------------------------------------------------
// Workspace layout (halfs):
//   [0, ED_SZ)      : Ed (f16, padded 176)   dead after K3
//   [+, +P_SZ)      : P  (f16, padded 176)   dead after K4
// Total = 14.6 MB.
// ---------------------------------------------------------------------------
extern "C" void kernel_launch(void* const* d_in, const int* in_sizes, int n_in,
                              void* d_out, int out_size, void* d_ws, size_t ws_size,
                              hipStream_t stream) {
    const float* x  = (const float*)d_in[0];   // [128,128,170,12] f32
    const float* Es = (const float*)d_in[1];   // [128,170] f32
    float* out = (float*)d_out;                // [170,170] f32

    _Float16* Ed = (_Float16*)d_ws;
    _Float16* P  = Ed + ED_SZ;

    k2_fused<<<dim3(6, 128), 256, 0, stream>>>(x, Es, Ed);
    k3_scores_mfma<<<dim3(6, 128), 256, 0, stream>>>(Ed, P);
    k4_mean_thresh<<<113, 256, 0, stream>>>(P, out);
}

// Round 2
// 225.065 us; speedup vs baseline: 1.1282x; 1.1282x over previous
//
#include <hip/hip_runtime.h>
#include <math.h>

// Problem constants
#define NB 128     // batch
#define NC 128     // channels
#define NN 170     // nodes
#define NT 12      // length
#define MP 176     // padded row stride for Ed/P (halfs); 176*2B = 352B, 16B-aligned rows
#define MEST 192   // Est padded rows (12 col-tiles of 16 for the Ed MFMA)

// Workspace regions (halfs)
#define EST_SZ ((size_t)MEST * NC)         //    24,576 halfs (48 KB)
#define XS_SZ  ((size_t)NB * NC * NN)      // 2,785,280 halfs (5.6 MB)
#define ED_SZ  ((size_t)NB * NN * MP)      // 3,829,760 halfs (7.3 MB)
#define P_SZ   ((size_t)NB * NN * MP)      // 3,829,760 halfs (7.3 MB)

// MFMA fragment / accumulator types (16x16x32 f16: 8 halfs per operand lane)
typedef _Float16 h8 __attribute__((ext_vector_type(8)));
typedef _Float16 h4 __attribute__((ext_vector_type(4)));
typedef __fp16   g2 __attribute__((ext_vector_type(2)));  // cvt_pkrtz return type
typedef float    f4 __attribute__((ext_vector_type(4)));

// tanh via hw exp+rcp: ~6 VALU ops vs ~30+ for libm tanhf. rel err ~1e-6.
__device__ __forceinline__ float fast_tanh(float x) {
    float cx = fminf(fmaxf(x, -15.f), 15.f);        // avoid inf/inf
    float e  = __expf(2.f * cx);                    // v_exp_f32
    return (e - 1.f) * __builtin_amdgcn_rcpf(e + 1.f);
}

// ---------------------------------------------------------------------------
// K0t: Est[m][c] = f16(Es[c][m]) for m<170, zero rows 170..191. The zero rows
// make Ed's pad cols [170,176) come out as tanh(0)=0, which K3's GEMM needs.
// 87 KB read (column-strided, L2), 48 KB write. ~1 us.
// ---------------------------------------------------------------------------
__global__ __launch_bounds__(256) void k0t_transpose_es(const float* __restrict__ Es,
                                                        _Float16* __restrict__ Est) {
    int idx = blockIdx.x * 256 + threadIdx.x;       // [0, 192*128)
    if (idx >= MEST * NC) return;
    int m = idx >> 7, c = idx & 127;
    Est[idx] = (m < NN) ? (_Float16)Es[c * NN + m] : (_Float16)0.f;
}

// ---------------------------------------------------------------------------
// K1: xs[b][c][n] = f16(sum_t x[b][c][n][t]). Barrier-free streaming kernel —
// this carries the 133.7 MB x read that dominated the old fused k2, but with
// full-occupancy grid-stride structure (no LDS, no syncs, 8 blocks/CU
// resident) so it runs at HBM rate instead of barrier-latency rate.
// Each thread: 2 consecutive n (6 float4 = 96B contiguous read), one packed
// 4B f16x2 store. 1,392,640 threads = 5440 blocks exactly.
// ---------------------------------------------------------------------------
__global__ __launch_bounds__(256) void k1_tsum(const float* __restrict__ x,
                                               _Float16* __restrict__ xs) {
    unsigned tid = blockIdx.x * 256 + threadIdx.x;  // [0, 128*128*85)
    unsigned bc = tid / 85u;                        // (b*NC + c)
    unsigned p  = tid - bc * 85u;                   // n-pair index, n = 2p
    const float4* q = reinterpret_cast<const float4*>(
        x + (size_t)bc * (NN * NT) + (size_t)p * (2 * NT));
    float4 f0 = q[0], f1 = q[1], f2 = q[2];         // n = 2p
    float4 f3 = q[3], f4v = q[4], f5 = q[5];        // n = 2p+1
    float s0 = ((f0.x + f0.y) + (f0.z + f0.w))
             + ((f1.x + f1.y) + (f1.z + f1.w))
             + ((f2.x + f2.y) + (f2.z + f2.w));
    float s1 = ((f3.x + f3.y) + (f3.z + f3.w))
             + ((f4v.x + f4v.y) + (f4v.z + f4v.w))
             + ((f5.x + f5.y) + (f5.z + f5.w));
    g2 pk = __builtin_amdgcn_cvt_pkrtz(s0, s1);
    *reinterpret_cast<g2*>(xs + (size_t)bc * NN + 2 * p) = pk;  // 4B store
}

// ---------------------------------------------------------------------------
// K2 (MFMA): Ed[b][n][m] = tanh( sum_c xs[b][c][n] * Est[m][c] ).
// Same HW-verified A·B^T pattern as K3 (a-frag/b-frag both row-major-in-k,
// 8 contiguous k at quad*8; D: col=lane&15, row=quad*4+reg).
//  - A = xs[b][:, n-tile]^T staged transposed through a 2.5 KB LDS tile
//    (read [c][n] coalesced, ds_write_b16 to [n][c], stride 40 halfs —
//    same stride/bank pattern as K3's proven Eh).
//  - B-frags read straight from Est (L2-hot, 48 KB shared by all blocks);
//    no LDS staging for B at all.
//  - 4 k-chunks of 32 channels; 4 waves x (2 row-tiles x 3 col-tiles)
//    cover 32n x 192m; write guarded to n<170, m<176.
// Work per block is tiny (24 mfma/wave): expect 2-4 us total.
// ---------------------------------------------------------------------------
__global__ __launch_bounds__(256) void k2_ed_mfma(const _Float16* __restrict__ xs,
                                                  const _Float16* __restrict__ Est,
                                                  _Float16* __restrict__ Ed) {
    const int b = blockIdx.y, n0 = blockIdx.x * 32;
    const int t = threadIdx.x;
    const int lane = t & 63, wave = t >> 6;
    const int l15 = lane & 15, quad = lane >> 4;

    __shared__ __align__(16) _Float16 At[32 * 40];  // [n_local][c_chunk], stride 40 halfs

    const _Float16* __restrict__ xsb = xs + (size_t)b * NC * NN;

    f4 acc[2][3] = {};                              // 2 row-tiles x 3 col-tiles
    for (int c0 = 0; c0 < NC; c0 += 32) {
        __syncthreads();
        // Stage A transposed: 32c x 32n slots; thread handles 4.
        #pragma unroll
        for (int it = 0; it < 4; ++it) {
            int slot = t + it * 256;                // [0,1024)
            int c = slot >> 5, n = slot & 31;
            _Float16 v = (_Float16)0.f;
            if (n0 + n < NN)
                v = xsb[(size_t)(c0 + c) * NN + n0 + n];
            At[n * 40 + c] = v;
        }
        __syncthreads();
        const int ko = quad * 8;                    // k-offset within chunk
        h8 a0 = *reinterpret_cast<const h8*>(&At[l15 * 40 + ko]);
        h8 a1 = *reinterpret_cast<const h8*>(&At[(16 + l15) * 40 + ko]);
        #pragma unroll
        for (int ci = 0; ci < 3; ++ci) {
            int kc = (wave * 3 + ci) * 16 + l15;    // B row (= Ed col m)
            h8 bf = *reinterpret_cast<const h8*>(Est + (size_t)kc * NC + c0 + ko);
            acc[0][ci] = __builtin_amdgcn_mfma_f32_16x16x32_f16(a0, bf, acc[0][ci], 0, 0, 0);
            acc[1][ci] = __builtin_amdgcn_mfma_f32_16x16x32_f16(a1, bf, acc[1][ci], 0, 0, 0);
        }
    }

    // Epilogue: tanh -> f16 scatter. 16 lanes of a (quad,reg) row write 32B
    // contiguous along m.
    #pragma unroll
    for (int rt = 0; rt < 2; ++rt)
        #pragma unroll
        for (int ci = 0; ci < 3; ++ci) {
            int m = (wave * 3 + ci) * 16 + l15;
            if (m >= MP) continue;
            #pragma unroll
            for (int reg = 0; reg < 4; ++reg) {
                int n = n0 + rt * 16 + quad * 4 + reg;
                if (n >= NN) continue;
                Ed[((size_t)(b * NN + n)) * MP + m] = (_Float16)fast_tanh(acc[rt][ci][reg]);
            }
        }
}

// ---------------------------------------------------------------------------
// K3 (MFMA): scores = relu(Ed[b]·Ed[b]^T / sqrt(C)), row softmax, write P (f16).
// Unchanged from round 1 (verified passing).
// ---------------------------------------------------------------------------
__global__ __launch_bounds__(256) void k3_scores_mfma(const _Float16* __restrict__ Ed,
                                                      _Float16* __restrict__ P) {
    const int b = blockIdx.y, r0 = blockIdx.x * 32;
    const int t = threadIdx.x;
    const int lane = t & 63, wave = t >> 6;
    const int l15 = lane & 15, quad = lane >> 4;

    __shared__ __align__(16) _Float16 Eh[192 * 40];  // [k-row][chunk k], stride 40 halfs
    __shared__ __align__(16) float    Sc[32 * 204];  // [n_local][k], stride 204

    const _Float16* __restrict__ Edb = Ed + (size_t)b * NN * MP;

    f4 acc[2][3] = {};                               // 2 row-tiles x 3 col-tiles
    for (int mc = 0; mc < 192; mc += 32) {
        __syncthreads();
        // Stage: 192 rows x 4 h8-slots = 768 16B copies -> 3 iters/thread.
        #pragma unroll
        for (int it = 0; it < 3; ++it) {
            int idx = t + it * 256;                  // [0,768)
            int row = idx >> 2, q = idx & 3;
            int col = mc + q * 8;
            h8 v = {};
            if (row < NN && col < MP)                // col mult of 8; col<176 => +7 in-bounds
                v = *reinterpret_cast<const h8*>(Edb + (size_t)row * MP + col);
            *reinterpret_cast<h8*>(&Eh[row * 40 + q * 8]) = v;   // 16B ds_write
        }
        __syncthreads();
        const int ko = quad * 8;                     // k-offset within chunk
        h8 a0 = *reinterpret_cast<const h8*>(&Eh[(r0 + l15) * 40 + ko]);
        h8 a1 = *reinterpret_cast<const h8*>(&Eh[(r0 + 16 + l15) * 40 + ko]);
        #pragma unroll
        for (int ci = 0; ci < 3; ++ci) {
            int kc = (wave * 3 + ci) * 16 + l15;     // B base row (= score col)
            h8 bf = *reinterpret_cast<const h8*>(&Eh[kc * 40 + ko]);
            acc[0][ci] = __builtin_amdgcn_mfma_f32_16x16x32_f16(a0, bf, acc[0][ci], 0, 0, 0);
            acc[1][ci] = __builtin_amdgcn_mfma_f32_16x16x32_f16(a1, bf, acc[1][ci], 0, 0, 0);
        }
    }

    // Scatter scaled+relu scores to Sc.
    const float scale = 0.08838834764831845f;        // 1/sqrt(128)
    #pragma unroll
    for (int rt = 0; rt < 2; ++rt)
        #pragma unroll
        for (int ci = 0; ci < 3; ++ci) {
            int col = (wave * 3 + ci) * 16 + l15;
            #pragma unroll
            for (int reg = 0; reg < 4; ++reg) {
                int rloc = rt * 16 + quad * 4 + reg;
                Sc[rloc * 204 + col] = fmaxf(acc[rt][ci][reg] * scale, 0.f);
            }
        }
    __syncthreads();

    // Softmax: wave w owns rows w*8 .. w*8+7. relu => valid values >= 0.
    for (int rr = 0; rr < 8; ++rr) {
        int r = wave * 8 + rr;
        int n = r0 + r;
        if (n >= NN) continue;                       // uniform per iteration
        float v0 = Sc[r * 204 + lane];
        float v1 = Sc[r * 204 + lane + 64];
        int  k2i = lane + 128;
        bool has2 = (k2i < NN);
        float v2 = has2 ? Sc[r * 204 + k2i] : -1.f;
        float m = fmaxf(fmaxf(v0, v1), v2);
        #pragma unroll
        for (int off = 32; off; off >>= 1) m = fmaxf(m, __shfl_xor(m, off, 64));
        float e0 = __expf(v0 - m);
        float e1 = __expf(v1 - m);
        float e2 = has2 ? __expf(v2 - m) : 0.f;
        float s = e0 + e1 + e2;
        #pragma unroll
        for (int off = 32; off; off >>= 1) s += __shfl_xor(s, off, 64);
        float inv = 1.f / s;
        _Float16* Pr = P + ((size_t)(b * NN + n)) * MP;
        Pr[lane]      = (_Float16)(e0 * inv);
        Pr[lane + 64] = (_Float16)(e1 * inv);
        if (has2) Pr[k2i] = (_Float16)(e2 * inv);
    }
}

// ---------------------------------------------------------------------------
// K4: mean over batch + threshold in one pass (unchanged from round 1).
// ---------------------------------------------------------------------------
__global__ __launch_bounds__(256) void k4_mean_thresh(const _Float16* __restrict__ P,
                                                      float* __restrict__ out) {
    int p = blockIdx.x * 256 + threadIdx.x;
    if (p >= NN * NN) return;
    int n = p / NN, k = p - n * NN;
    const _Float16* base = P + (size_t)n * MP + k;
    float s0 = 0.f, s1 = 0.f, s2 = 0.f, s3 = 0.f;
    #pragma unroll
    for (int b = 0; b < NB; b += 4) {
        s0 += (float)base[(size_t)(b + 0) * NN * MP];
        s1 += (float)base[(size_t)(b + 1) * NN * MP];
        s2 += (float)base[(size_t)(b + 2) * NN * MP];
        s3 += (float)base[(size_t)(b + 3) * NN * MP];
    }
    float s = (s0 + s1) + (s2 + s3);
    out[p] = (s * (1.f / 128.f) > 0.5f) ? 1.f : 0.f;
}

// ---------------------------------------------------------------------------
// Workspace layout (halfs):
//   [0, EST_SZ)   : Est (f16, [192][128])        live through K2
//   [+, +XS_SZ)   : xs  (f16, [b][c][170])       dead after K2
//   [+, +ED_SZ)   : Ed  (f16, padded 176)        dead after K3
//   [+, +P_SZ)    : P   (f16, padded 176)        dead after K4
// Total = 20.9 MB (round 0 used 31.65 MB successfully).
// ---------------------------------------------------------------------------
extern "C" void kernel_launch(void* const* d_in, const int* in_sizes, int n_in,
                              void* d_out, int out_size, void* d_ws, size_t ws_size,
                              hipStream_t stream) {
    const float* x  = (const float*)d_in[0];   // [128,128,170,12] f32
    const float* Es = (const float*)d_in[1];   // [128,170] f32
    float* out = (float*)d_out;                // [170,170] f32

    _Float16* Est = (_Float16*)d_ws;
    _Float16* xs  = Est + EST_SZ;
    _Float16* Ed  = xs + XS_SZ;
    _Float16* P   = Ed + ED_SZ;

    k0t_transpose_es<<<96, 256, 0, stream>>>(Es, Est);
    k1_tsum<<<5440, 256, 0, stream>>>(x, xs);
    k2_ed_mfma<<<dim3(6, 128), 256, 0, stream>>>(xs, Est, Ed);
    k3_scores_mfma<<<dim3(6, 128), 256, 0, stream>>>(Ed, P);
    k4_mean_thresh<<<113, 256, 0, stream>>>(P, out);
}